// Round 2
// baseline (1474.686 us; speedup 1.0000x reference)
//
#include <hip/hip_runtime.h>
#include <hip/hip_bf16.h>
#include <cstdint>

#define B_ 512
#define T_ 48
#define N_ 62
#define F_ 5
#define E_ 496
#define H_ 512
#define NF_ 310      // N*F
#define SEQP 320     // padded seq row (310 -> 320)
#define KPAD 832     // 320 + 512
#define EPS_ 1e-5f
#define TCH 6        // t-steps per cheb block (48/8 chunks)

typedef __attribute__((ext_vector_type(8))) short short8;
typedef __attribute__((ext_vector_type(4))) float f32x4;

__device__ __forceinline__ float sigm(float x)  { return 1.f / (1.f + __expf(-x)); }
__device__ __forceinline__ float tanhf_(float x){ return 2.f / (1.f + __expf(-2.f*x)) - 1.f; }

// ---------------- ChebConv (K=3) + BN partial stats, one block per (graph, t-chunk) ----------------
__global__ __launch_bounds__(320) void k_cheb(
    const float* __restrict__ x, const int* __restrict__ esrc, const int* __restrict__ edst,
    const float* __restrict__ ew, const float* __restrict__ Wc, const float* __restrict__ bc,
    float* __restrict__ cheb, float* __restrict__ bps, float* __restrict__ bpq)
{
  __shared__ float A[N_*N_];
  __shared__ float dinv[N_];
  __shared__ float X0[NF_], T1s[NF_], T2s[NF_], OUT[NF_];
  __shared__ float wcs[75];
  const int tid = threadIdx.x;
  const int b = blockIdx.x;
  const int t0 = blockIdx.y * TCH;

  for (int i = tid; i < N_*N_; i += 320) A[i] = 0.f;
  __syncthreads();
  for (int e = tid; e < E_; e += 320) {
    int s = esrc[b*E_ + e], d = edst[b*E_ + e];
    atomicAdd(&A[d*N_ + s], ew[b*E_ + e]);
  }
  __syncthreads();
  if (tid < N_) {
    float s = 0.f;
    for (int m = 0; m < N_; ++m) s += A[tid*N_ + m];
    dinv[tid] = (s > 0.f) ? rsqrtf(s) : 0.f;
  }
  __syncthreads();
  for (int i = tid; i < N_*N_; i += 320) {
    int n = i / N_, m = i % N_;
    A[i] = -dinv[n] * A[i] * dinv[m];   // Lhat in place
  }
  __syncthreads();

  const int n = tid / F_, f = tid % F_;

  for (int t = t0; t < t0 + TCH; ++t) {
    if (tid < NF_) X0[tid] = x[((size_t)b*T_ + t)*NF_ + tid];
    if (tid < 75)  wcs[tid] = Wc[t*75 + tid];      // [k][f][g]
    __syncthreads();
    if (tid < NF_) {
      float t1 = 0.f;
      #pragma unroll
      for (int m = 0; m < N_; ++m) t1 = fmaf(A[n*N_ + m], X0[m*F_ + f], t1);
      T1s[tid] = t1;
    }
    __syncthreads();
    if (tid < NF_) {
      float t2 = 0.f;
      #pragma unroll
      for (int m = 0; m < N_; ++m) t2 = fmaf(A[n*N_ + m], T1s[m*F_ + f], t2);
      T2s[tid] = 2.f*t2 - X0[tid];
    }
    __syncthreads();
    if (tid < NF_) {     // here (n, g=f)
      float v = bc[t*F_ + f];
      #pragma unroll
      for (int ff = 0; ff < F_; ++ff) {
        v = fmaf(X0 [n*F_ + ff], wcs[      ff*F_ + f], v);
        v = fmaf(T1s[n*F_ + ff], wcs[25 +  ff*F_ + f], v);
        v = fmaf(T2s[n*F_ + ff], wcs[50 +  ff*F_ + f], v);
      }
      OUT[tid] = v;
      cheb[((size_t)t*B_ + b)*NF_ + tid] = v;
    }
    __syncthreads();
    if (tid < F_) {
      float s = 0.f, q = 0.f;
      #pragma unroll
      for (int nn = 0; nn < N_; ++nn) { float v = OUT[nn*F_ + tid]; s += v; q += v*v; }
      bps[(t*F_ + tid)*B_ + b] = s;
      bpq[(t*F_ + tid)*B_ + b] = q;
    }
    __syncthreads();
  }
}

// ---------------- finalize BN scale/shift per (t,f) ----------------
__global__ __launch_bounds__(64) void k_bnfin(
    const float* __restrict__ bps, const float* __restrict__ bpq,
    const float* __restrict__ bng, const float* __restrict__ bnb,
    float* __restrict__ alpha, float* __restrict__ bet)
{
  const int tf = blockIdx.x;
  const int lane = threadIdx.x;
  float s = 0.f, q = 0.f;
  for (int i = lane; i < B_; i += 64) { s += bps[tf*B_ + i]; q += bpq[tf*B_ + i]; }
  #pragma unroll
  for (int off = 32; off; off >>= 1) { s += __shfl_down(s, off); q += __shfl_down(q, off); }
  if (lane == 0) {
    const float cnt = (float)(B_*N_);
    float mu = s / cnt;
    float var = q / cnt - mu*mu;
    float al = bng[tf] * rsqrtf(var + EPS_);
    alpha[tf] = al;
    bet[tf] = bnb[tf] - mu*al;
  }
}

// ---------------- BN apply + pack to bf16 padded sequence [t][b][320] ----------------
__global__ __launch_bounds__(256) void k_seq(
    const float* __restrict__ cheb, const float* __restrict__ alpha, const float* __restrict__ bet,
    __hip_bfloat16* __restrict__ seqb)
{
  int idx = blockIdx.x*256 + threadIdx.x;     // T*B*320
  int k = idx % SEQP;
  int tb = idx / SEQP;                        // t*B + b
  float v = 0.f;
  if (k < NF_) {
    int t = tb / B_;
    int tf = t*F_ + (k % F_);
    v = cheb[(size_t)tb*NF_ + k] * alpha[tf] + bet[tf];
  }
  seqb[idx] = __float2bfloat16(v);
}

// ---------------- build bf16 W_cat (2048 x 832): [W_ih | pad | W_hh] ----------------
__global__ __launch_bounds__(256) void k_wcat(
    const float* __restrict__ Wih, const float* __restrict__ Whh,
    __hip_bfloat16* __restrict__ Wcat)
{
  int j = blockIdx.x;                          // 0..2047
  for (int k = threadIdx.x; k < KPAD; k += 256) {
    float v = 0.f;
    if (k < NF_) v = Wih[(size_t)j*NF_ + k];
    else if (k >= SEQP) v = Whh[(size_t)j*H_ + (k - SEQP)];
    Wcat[(size_t)j*KPAD + k] = __float2bfloat16(v);
  }
}

// ---------------- one LSTM step: gate-per-wave MFMA GEMM + fused cell update ----------------
// grid (B/16, H/16) = (32, 32), 256 threads = 4 waves, wave g computes gate g.
__global__ __launch_bounds__(256) void k_step(
    const __hip_bfloat16* __restrict__ seqt,   // (B, 320)
    const __hip_bfloat16* __restrict__ hin,    // (B, 512)
    const __hip_bfloat16* __restrict__ Wcat,   // (2048, 832)
    const float* __restrict__ bih, const float* __restrict__ bhh,
    float* __restrict__ cbuf, float* __restrict__ y,
    __hip_bfloat16* __restrict__ hout, int t)
{
  const int tid = threadIdx.x;
  const int lane = tid & 63;
  const int gate = tid >> 6;                   // wave index == gate
  const int l16 = lane & 15;
  const int lhi = lane >> 4;
  const int b0 = blockIdx.x * 16;
  const int j0 = blockIdx.y * 16;

  const short* sseq = (const short*)seqt;
  const short* sh   = (const short*)hin;
  const short* sw   = (const short*)Wcat;

  const int arow = b0 + l16;
  const short* ap0 = sseq + (size_t)arow*SEQP + lhi*8;
  const short* ap1 = sh   + (size_t)arow*H_   + lhi*8;
  const short* bp  = sw + (size_t)(gate*H_ + j0 + l16)*KPAD + lhi*8;

  f32x4 acc = {0.f,0.f,0.f,0.f};
  #pragma unroll
  for (int kk = 0; kk < 10; ++kk) {            // seq part of K
    short8 a = *(const short8*)(ap0 + kk*32);
    short8 w = *(const short8*)(bp + kk*32);
    acc = __builtin_amdgcn_mfma_f32_16x16x32_bf16(a, w, acc, 0, 0, 0);
  }
  #pragma unroll
  for (int kk = 0; kk < 16; ++kk) {            // h part of K
    short8 a = *(const short8*)(ap1 + kk*32);
    short8 w = *(const short8*)(bp + (kk+10)*32);
    acc = __builtin_amdgcn_mfma_f32_16x16x32_bf16(a, w, acc, 0, 0, 0);
  }

  // D layout: col = lane&15, row = 4*(lane>>4)+r
  __shared__ float gl[4][16][16];              // [gate][row][col]
  #pragma unroll
  for (int r = 0; r < 4; ++r) gl[gate][lhi*4 + r][l16] = acc[r];
  __syncthreads();

  // epilogue: one output element per thread
  const int row = tid >> 4, col = tid & 15;
  const int bb = b0 + row, j = j0 + col;
  float ig = sigm  (gl[0][row][col] + bih[       j] + bhh[       j]);
  float fg = sigm  (gl[1][row][col] + bih[H_   + j] + bhh[H_   + j]);
  float gg = tanhf_(gl[2][row][col] + bih[2*H_ + j] + bhh[2*H_ + j]);
  float og = sigm  (gl[3][row][col] + bih[3*H_ + j] + bhh[3*H_ + j]);
  float cn = fg * cbuf[bb*H_ + j] + ig*gg;
  cbuf[bb*H_ + j] = cn;
  float h = og * tanhf_(cn);
  y[((size_t)bb*T_ + t)*H_ + j] = h;
  hout[bb*H_ + j] = __float2bfloat16(h);
}

// ---------------- BN1 partial stats over (B,H) per t ----------------
__global__ __launch_bounds__(256) void k_bn1part(
    const float* __restrict__ y, float* __restrict__ bn1s, float* __restrict__ bn1q)
{
  const int t = blockIdx.x, ch = blockIdx.y, tid = threadIdx.x;
  float s = 0.f, q = 0.f;
  for (int i = tid; i < 64*H_; i += 256) {
    int b = ch*64 + (i >> 9);
    float v = y[((size_t)b*T_ + t)*H_ + (i & 511)];
    s += v; q += v*v;
  }
  __shared__ float rs[256], rq[256];
  rs[tid] = s; rq[tid] = q;
  __syncthreads();
  for (int o = 128; o; o >>= 1) {
    if (tid < o) { rs[tid] += rs[tid+o]; rq[tid] += rq[tid+o]; }
    __syncthreads();
  }
  if (tid == 0) { bn1s[t*8 + ch] = rs[0]; bn1q[t*8 + ch] = rq[0]; }
}

// ---------------- head: fold BN1 + (B, T*H) @ Wl^T + bl, one block per b ----------------
__global__ __launch_bounds__(256) void k_head(
    const float* __restrict__ y, const float* __restrict__ bn1s, const float* __restrict__ bn1q,
    const float* __restrict__ g1, const float* __restrict__ be1,
    const float* __restrict__ Wl, const float* __restrict__ bl, float* __restrict__ out)
{
  const int b = blockIdx.x, tid = threadIdx.x;
  __shared__ float al1[T_], bt1[T_];
  if (tid < T_) {
    float s = 0.f, q = 0.f;
    #pragma unroll
    for (int ch = 0; ch < 8; ++ch) { s += bn1s[tid*8 + ch]; q += bn1q[tid*8 + ch]; }
    const float cnt = (float)(B_*H_);
    float mu = s / cnt, var = q / cnt - mu*mu;
    float al = g1[tid] * rsqrtf(var + EPS_);
    al1[tid] = al; bt1[tid] = be1[tid] - mu*al;
  }
  __syncthreads();
  float a0 = 0.f, a1 = 0.f, a2 = 0.f;
  const float* yb = y + (size_t)b*(T_*H_);
  for (int i = tid; i < T_*H_; i += 256) {
    int t = i >> 9;
    float yn = yb[i]*al1[t] + bt1[t];
    a0 = fmaf(yn, Wl[i],            a0);
    a1 = fmaf(yn, Wl[T_*H_ + i],    a1);
    a2 = fmaf(yn, Wl[2*T_*H_ + i],  a2);
  }
  __shared__ float red[256];
  red[tid] = a0; __syncthreads();
  for (int o = 128; o; o >>= 1) { if (tid < o) red[tid] += red[tid+o]; __syncthreads(); }
  if (!tid) out[b*3 + 0] = red[0] + bl[0];
  __syncthreads();
  red[tid] = a1; __syncthreads();
  for (int o = 128; o; o >>= 1) { if (tid < o) red[tid] += red[tid+o]; __syncthreads(); }
  if (!tid) out[b*3 + 1] = red[0] + bl[1];
  __syncthreads();
  red[tid] = a2; __syncthreads();
  for (int o = 128; o; o >>= 1) { if (tid < o) red[tid] += red[tid+o]; __syncthreads(); }
  if (!tid) out[b*3 + 2] = red[0] + bl[2];
}

extern "C" void kernel_launch(void* const* d_in, const int* in_sizes, int n_in,
                              void* d_out, int out_size, void* d_ws, size_t ws_size,
                              hipStream_t stream)
{
  (void)in_sizes; (void)n_in; (void)out_size;
  const float* x   = (const float*)d_in[0];
  const int* esrc  = (const int*)d_in[1];
  const int* edst  = (const int*)d_in[2];
  const float* ew  = (const float*)d_in[3];
  const float* Wc  = (const float*)d_in[4];
  const float* bc  = (const float*)d_in[5];
  const float* bng = (const float*)d_in[6];
  const float* bnb = (const float*)d_in[7];
  const float* Wih = (const float*)d_in[8];
  const float* Whh = (const float*)d_in[9];
  const float* bih = (const float*)d_in[10];
  const float* bhh = (const float*)d_in[11];
  const float* g1  = (const float*)d_in[12];
  const float* be1 = (const float*)d_in[13];
  const float* Wl  = (const float*)d_in[14];
  const float* bl  = (const float*)d_in[15];
  float* out = (float*)d_out;

  char* ws = (char*)d_ws;
  size_t off = 0;
  auto alloc = [&](size_t bytes) {
    void* p = ws + off;
    off += (bytes + 255) & ~(size_t)255;
    return p;
  };
  float* cheb = (float*)alloc(sizeof(float)*(size_t)T_*B_*NF_);
  float* bps  = (float*)alloc(sizeof(float)*T_*F_*B_);
  float* bpq  = (float*)alloc(sizeof(float)*T_*F_*B_);
  float* alpha= (float*)alloc(sizeof(float)*T_*F_);
  float* bet  = (float*)alloc(sizeof(float)*T_*F_);
  __hip_bfloat16* seqb = (__hip_bfloat16*)alloc(sizeof(__hip_bfloat16)*(size_t)T_*B_*SEQP);
  __hip_bfloat16* Wcat = (__hip_bfloat16*)alloc(sizeof(__hip_bfloat16)*(size_t)4*H_*KPAD);
  __hip_bfloat16* h0   = (__hip_bfloat16*)alloc(sizeof(__hip_bfloat16)*B_*H_);
  __hip_bfloat16* h1   = (__hip_bfloat16*)alloc(sizeof(__hip_bfloat16)*B_*H_);
  float* cbuf = (float*)alloc(sizeof(float)*B_*H_);
  float* y    = (float*)alloc(sizeof(float)*(size_t)B_*T_*H_);
  float* bn1s = (float*)alloc(sizeof(float)*T_*8);
  float* bn1q = (float*)alloc(sizeof(float)*T_*8);
  if (ws_size < off) return;   // workspace too small -> fail loudly (output stays poisoned)

  hipMemsetAsync(h0,   0, sizeof(__hip_bfloat16)*B_*H_, stream);
  hipMemsetAsync(cbuf, 0, sizeof(float)*B_*H_, stream);

  k_cheb<<<dim3(B_, T_/TCH), 320, 0, stream>>>(x, esrc, edst, ew, Wc, bc, cheb, bps, bpq);
  k_bnfin<<<T_*F_, 64, 0, stream>>>(bps, bpq, bng, bnb, alpha, bet);
  k_seq<<<(T_*B_*SEQP)/256, 256, 0, stream>>>(cheb, alpha, bet, seqb);
  k_wcat<<<4*H_, 256, 0, stream>>>(Wih, Whh, Wcat);

  const __hip_bfloat16* hin = h0;
  __hip_bfloat16* hout = h1;
  for (int t = 0; t < T_; ++t) {
    k_step<<<dim3(B_/16, H_/16), 256, 0, stream>>>(
        seqb + (size_t)t*B_*SEQP, hin, Wcat, bih, bhh, cbuf, y, hout, t);
    __hip_bfloat16* nxt = (hout == h1) ? h0 : h1;
    hin = hout;
    hout = nxt;
  }

  k_bn1part<<<dim3(T_, 8), 256, 0, stream>>>(y, bn1s, bn1q);
  k_head<<<B_, 256, 0, stream>>>(y, bn1s, bn1q, g1, be1, Wl, bl, out);
}

// Round 5
// 1426.201 us; speedup vs baseline: 1.0340x; 1.0340x over previous
//
#include <hip/hip_runtime.h>
#include <hip/hip_bf16.h>
#include <cstdint>

#define B_ 512
#define T_ 48
#define N_ 62
#define F_ 5
#define E_ 496
#define H_ 512
#define NF_ 310      // N*F
#define SEQP 320     // padded seq row (310 -> 320)
#define KPAD 832     // 320 + 512
#define G4 2048      // 4*H
#define EPS_ 1e-5f
#define TC 24        // t-steps per cheb block (2 chunks)
#define LSTR 72      // LDS row stride in shorts (16B-aligned, conflict-light)

typedef __attribute__((ext_vector_type(8))) short short8;
typedef __attribute__((ext_vector_type(4))) short s16x4;
typedef __attribute__((ext_vector_type(4))) float f32x4;

__device__ __forceinline__ float sigm(float x)  { return 1.f / (1.f + __expf(-x)); }
__device__ __forceinline__ float tanhf_(float x){ return 2.f / (1.f + __expf(-2.f*x)) - 1.f; }

__device__ __forceinline__ short f2b(float v) {   // f32 -> bf16 bits, RN-even
  unsigned int u = __builtin_bit_cast(unsigned int, v);
  unsigned int r = (u + 0x7fffu + ((u >> 16) & 1u)) >> 16;
  return (short)r;
}
__device__ __forceinline__ float b2f(short s) {   // bf16 bits -> f32
  unsigned int u = ((unsigned int)(unsigned short)s) << 16;
  return __builtin_bit_cast(float, u);
}

// ============ ChebConv K=3 via MFMA + BN partial stats; block = (graph, 24-t chunk) ============
__global__ __launch_bounds__(512) void k_cheb(
    const float* __restrict__ x, const int* __restrict__ esrc, const int* __restrict__ edst,
    const float* __restrict__ ew, const float* __restrict__ Wc, const float* __restrict__ bc,
    float* __restrict__ cheb, float* __restrict__ bps, float* __restrict__ bpq)
{
  __shared__ __align__(16) short Lb [64*LSTR];    // Lhat bf16, [n][m], zero-padded to 64x64
  __shared__ __align__(16) short Xt [128*LSTR];   // X^T  bf16, [c=tl*5+f][m=n]
  __shared__ __align__(16) short T1t[128*LSTR];   // T1^T bf16
  __shared__ __align__(16) short T2t[128*LSTR];   // T2^T bf16 (start doubles as f32 A)
  __shared__ float dinv[N_];
  float* Af = (float*)T2t;                        // 62*62*4 = 15376 B <= 18432 B

  const int tid = threadIdx.x;
  const int b = blockIdx.x;
  const int t0 = blockIdx.y * TC;

  // zero-init (pad regions must be 0 for MFMA)
  for (int i = tid; i < 64*LSTR;  i += 512) Lb[i] = 0;
  for (int i = tid; i < 128*LSTR; i += 512) Xt[i] = 0;
  for (int i = tid; i < N_*N_;    i += 512) Af[i] = 0.f;
  __syncthreads();

  // build A + load X^T
  for (int e = tid; e < E_; e += 512)
    atomicAdd(&Af[edst[b*E_ + e]*N_ + esrc[b*E_ + e]], ew[b*E_ + e]);
  for (int i = tid; i < TC*NF_; i += 512) {
    int tl = i / NF_, nf = i - tl*NF_;
    float v = x[((size_t)b*T_ + t0 + tl)*NF_ + nf];
    int n = nf / F_, f = nf - n*F_;
    Xt[(tl*F_ + f)*LSTR + n] = f2b(v);
  }
  __syncthreads();

  if (tid < N_) {
    float s = 0.f;
    for (int m = 0; m < N_; ++m) s += Af[tid*N_ + m];
    dinv[tid] = (s > 0.f) ? rsqrtf(s) : 0.f;
  }
  __syncthreads();
  for (int i = tid; i < N_*N_; i += 512) {
    int n = i / N_, m = i - n*N_;
    Lb[n*LSTR + m] = f2b(-dinv[n] * Af[i] * dinv[m]);
  }
  __syncthreads();                                // Af dead from here; T2t reusable

  const int w = tid >> 6, lane = tid & 63, l16 = lane & 15, lhi = lane >> 4;
  const int mt  = w >> 1;                         // M-tile (n) 0..3
  const int ntb = (w & 1) * 4;                    // base N-tile (c) 0..7

  // ---- T1 = Lhat @ X : D[n][c] = sum_m Lb[n][m] * Xt[c][m] ----
  {
    f32x4 acc[4];
    #pragma unroll
    for (int i = 0; i < 4; ++i) acc[i] = f32x4{0.f,0.f,0.f,0.f};
    #pragma unroll
    for (int kc = 0; kc < 2; ++kc) {
      short8 a = *(const short8*)(Lb + (mt*16 + l16)*LSTR + kc*32 + lhi*8);
      #pragma unroll
      for (int i = 0; i < 4; ++i) {
        short8 bb = *(const short8*)(Xt + ((ntb+i)*16 + l16)*LSTR + kc*32 + lhi*8);
        acc[i] = __builtin_amdgcn_mfma_f32_16x16x32_bf16(a, bb, acc[i], 0, 0, 0);
      }
    }
    #pragma unroll
    for (int i = 0; i < 4; ++i) {
      int c = (ntb+i)*16 + l16, n = mt*16 + lhi*4;
      s16x4 pk;
      #pragma unroll
      for (int r = 0; r < 4; ++r) pk[r] = f2b(acc[i][r]);
      *(s16x4*)(T1t + c*LSTR + n) = pk;
    }
  }
  __syncthreads();

  // ---- T2 = 2*Lhat@T1 - X ----
  {
    f32x4 acc[4];
    #pragma unroll
    for (int i = 0; i < 4; ++i) acc[i] = f32x4{0.f,0.f,0.f,0.f};
    #pragma unroll
    for (int kc = 0; kc < 2; ++kc) {
      short8 a = *(const short8*)(Lb + (mt*16 + l16)*LSTR + kc*32 + lhi*8);
      #pragma unroll
      for (int i = 0; i < 4; ++i) {
        short8 bb = *(const short8*)(T1t + ((ntb+i)*16 + l16)*LSTR + kc*32 + lhi*8);
        acc[i] = __builtin_amdgcn_mfma_f32_16x16x32_bf16(a, bb, acc[i], 0, 0, 0);
      }
    }
    #pragma unroll
    for (int i = 0; i < 4; ++i) {
      int c = (ntb+i)*16 + l16, n = mt*16 + lhi*4;
      s16x4 xv = *(const s16x4*)(Xt + c*LSTR + n);
      s16x4 pk;
      #pragma unroll
      for (int r = 0; r < 4; ++r) pk[r] = f2b(2.f*acc[i][r] - b2f(xv[r]));
      *(s16x4*)(T2t + c*LSTR + n) = pk;
    }
  }
  __syncthreads();

  // ---- out[t][n][g] = bc + sum_f X*W0 + T1*W1 + T2*W2 ; + BN partials over n ----
  const int pair = tid >> 2, q = tid & 3;
  if (pair < TC*F_) {
    const int tl = pair / F_, g = pair - (pair/F_)*F_;
    const int t = t0 + tl;
    float w0[5], w1[5], w2[5];
    #pragma unroll
    for (int ff = 0; ff < 5; ++ff) {
      w0[ff] = Wc[t*75 +      ff*5 + g];
      w1[ff] = Wc[t*75 + 25 + ff*5 + g];
      w2[ff] = Wc[t*75 + 50 + ff*5 + g];
    }
    const float bias = bc[t*F_ + g];
    float ss = 0.f, qq = 0.f;
    float* chout = cheb + ((size_t)t*B_ + b)*NF_;
    #pragma unroll
    for (int grp = 0; grp < 4; ++grp) {
      int n4 = grp*16 + q*4;
      float o[4] = {bias, bias, bias, bias};
      #pragma unroll
      for (int ff = 0; ff < 5; ++ff) {
        int c = tl*F_ + ff;
        s16x4 xv = *(const s16x4*)(Xt  + c*LSTR + n4);
        s16x4 v1 = *(const s16x4*)(T1t + c*LSTR + n4);
        s16x4 v2 = *(const s16x4*)(T2t + c*LSTR + n4);
        #pragma unroll
        for (int i = 0; i < 4; ++i)
          o[i] += b2f(xv[i])*w0[ff] + b2f(v1[i])*w1[ff] + b2f(v2[i])*w2[ff];
      }
      #pragma unroll
      for (int i = 0; i < 4; ++i) {
        int n = n4 + i;
        if (n < N_) { chout[n*F_ + g] = o[i]; ss += o[i]; qq += o[i]*o[i]; }
      }
    }
    ss += __shfl_down(ss, 2, 4); ss += __shfl_down(ss, 1, 4);
    qq += __shfl_down(qq, 2, 4); qq += __shfl_down(qq, 1, 4);
    if (q == 0) { bps[(t*F_ + g)*B_ + b] = ss; bpq[(t*F_ + g)*B_ + b] = qq; }
  }
}

// ============ finalize BN scale/shift per (t,f) ============
__global__ __launch_bounds__(64) void k_bnfin(
    const float* __restrict__ bps, const float* __restrict__ bpq,
    const float* __restrict__ bng, const float* __restrict__ bnb,
    float* __restrict__ alpha, float* __restrict__ bet)
{
  const int tf = blockIdx.x;
  const int lane = threadIdx.x;
  float s = 0.f, q = 0.f;
  for (int i = lane; i < B_; i += 64) { s += bps[tf*B_ + i]; q += bpq[tf*B_ + i]; }
  #pragma unroll
  for (int off = 32; off; off >>= 1) { s += __shfl_down(s, off); q += __shfl_down(q, off); }
  if (lane == 0) {
    const float cnt = (float)(B_*N_);
    float mu = s / cnt;
    float var = q / cnt - mu*mu;
    float al = bng[tf] * rsqrtf(var + EPS_);
    alpha[tf] = al;
    bet[tf] = bnb[tf] - mu*al;
  }
}

// ============ BN apply + pack to bf16 padded sequence [t][b][320] ============
__global__ __launch_bounds__(256) void k_seq(
    const float* __restrict__ cheb, const float* __restrict__ alpha, const float* __restrict__ bet,
    __hip_bfloat16* __restrict__ seqb)
{
  int idx = blockIdx.x*256 + threadIdx.x;     // T*B*320
  int k = idx % SEQP;
  int tb = idx / SEQP;                        // t*B + b
  float v = 0.f;
  if (k < NF_) {
    int t = tb / B_;
    int tf = t*F_ + (k % F_);
    v = cheb[(size_t)tb*NF_ + k] * alpha[tf] + bet[tf];
  }
  seqb[idx] = __float2bfloat16(v);
}

// ============ weight prep: gate-interleaved rows j' = jh*4 + gate; K = [seq|pad|h] ============
__global__ __launch_bounds__(256) void k_prep(
    const float* __restrict__ Wih, const float* __restrict__ Whh,
    const float* __restrict__ bih, const float* __restrict__ bhh,
    __hip_bfloat16* __restrict__ Wcat, float* __restrict__ biasr)
{
  const int jp = blockIdx.x;                  // 0..2047
  const int g = jp & 3, jh = jp >> 2;
  const int jo = g*H_ + jh;
  for (int k = threadIdx.x; k < KPAD; k += 256) {
    float v = 0.f;
    if (k < NF_) v = Wih[(size_t)jo*NF_ + k];
    else if (k >= SEQP) v = Whh[(size_t)jo*H_ + (k - SEQP)];
    Wcat[(size_t)jp*KPAD + k] = __float2bfloat16(v);
  }
  if (threadIdx.x == 0) biasr[jp] = bih[jo] + bhh[jo];
}

// ============ LSTM step: gates = [seq_t|h] @ Wcat^T + biasr; fused cell update ============
// grid (G4/32=64, B/32=16): j-tile fastest so each XCD's L2 holds ~1/8 of Wcat.
// 256 thr = 4 waves; wave w -> (mtile w&1, ntile w>>1); block tile 32(b) x 32(j')
__global__ __launch_bounds__(256) void k_step(
    const __hip_bfloat16* __restrict__ seqt,   // (B, 320) bf16, this t
    const __hip_bfloat16* __restrict__ hin,    // (B, 512) bf16
    const __hip_bfloat16* __restrict__ Wcat,   // (2048, 832) gate-interleaved
    const float* __restrict__ biasr,           // (2048)
    float* __restrict__ cbuf, float* __restrict__ y,
    __hip_bfloat16* __restrict__ hout, int t)
{
  const int tid = threadIdx.x;
  const int w = tid >> 6, lane = tid & 63, l16 = lane & 15, lhi = lane >> 4;
  const int j0 = blockIdx.x * 32, b0 = blockIdx.y * 32;
  const int mt = w & 1, nt = w >> 1;

  const short* sa0 = (const short*)seqt + (size_t)(b0 + mt*16 + l16)*SEQP + lhi*8;
  const short* sa1 = (const short*)hin  + (size_t)(b0 + mt*16 + l16)*H_   + lhi*8;
  const short* sb  = (const short*)Wcat + (size_t)(j0 + nt*16 + l16)*KPAD + lhi*8;

  f32x4 acc = {0.f,0.f,0.f,0.f};
  #pragma unroll
  for (int kc = 0; kc < 10; ++kc) {            // seq part of K (320)
    short8 a  = *(const short8*)(sa0 + kc*32);
    short8 bb = *(const short8*)(sb + kc*32);
    acc = __builtin_amdgcn_mfma_f32_16x16x32_bf16(a, bb, acc, 0, 0, 0);
  }
  #pragma unroll
  for (int kc = 0; kc < 16; ++kc) {            // h part of K (512)
    short8 a  = *(const short8*)(sa1 + kc*32);
    short8 bb = *(const short8*)(sb + (10 + kc)*32);
    acc = __builtin_amdgcn_mfma_f32_16x16x32_bf16(a, bb, acc, 0, 0, 0);
  }

  __shared__ float gl[32][33];
  const int col = j0 + nt*16 + l16;
  const float bv = biasr[col];
  #pragma unroll
  for (int r = 0; r < 4; ++r) {
    const int rowl = mt*16 + lhi*4 + r;        // D: row = 4*(lane>>4)+r (+16*mt), col = lane&15
    gl[rowl][nt*16 + l16] = acc[r] + bv;
  }
  __syncthreads();

  // epilogue: 4 gate columns per hidden unit are adjacent (j' = jh*4 + gate)
  const int bl = tid >> 3, j8 = tid & 7;
  const int bb = b0 + bl, jh = (j0 >> 2) + j8;
  float iv = gl[bl][j8*4 + 0];
  float fv = gl[bl][j8*4 + 1];
  float gv = gl[bl][j8*4 + 2];
  float ov = gl[bl][j8*4 + 3];
  float cn = sigm(fv) * cbuf[bb*H_ + jh] + sigm(iv) * tanhf_(gv);
  cbuf[bb*H_ + jh] = cn;
  float h = sigm(ov) * tanhf_(cn);
  y[((size_t)bb*T_ + t)*H_ + jh] = h;
  hout[bb*H_ + jh] = __float2bfloat16(h);
}

// ============ BN1 partial stats over (B,H) per t ============
__global__ __launch_bounds__(256) void k_bn1part(
    const float* __restrict__ y, float* __restrict__ bn1s, float* __restrict__ bn1q)
{
  const int t = blockIdx.x, ch = blockIdx.y, tid = threadIdx.x;
  float s = 0.f, q = 0.f;
  for (int i = tid; i < 64*H_; i += 256) {
    int b = ch*64 + (i >> 9);
    float v = y[((size_t)b*T_ + t)*H_ + (i & 511)];
    s += v; q += v*v;
  }
  __shared__ float rs[256], rq[256];
  rs[tid] = s; rq[tid] = q;
  __syncthreads();
  for (int o = 128; o; o >>= 1) {
    if (tid < o) { rs[tid] += rs[tid+o]; rq[tid] += rq[tid+o]; }
    __syncthreads();
  }
  if (tid == 0) { bn1s[t*8 + ch] = rs[0]; bn1q[t*8 + ch] = rq[0]; }
}

// ============ head: fold BN1 + (B, T*H) @ Wl^T + bl ============
__global__ __launch_bounds__(256) void k_head(
    const float* __restrict__ y, const float* __restrict__ bn1s, const float* __restrict__ bn1q,
    const float* __restrict__ g1, const float* __restrict__ be1,
    const float* __restrict__ Wl, const float* __restrict__ bl, float* __restrict__ out)
{
  const int b = blockIdx.x, tid = threadIdx.x;
  __shared__ float al1[T_], bt1[T_];
  if (tid < T_) {
    float s = 0.f, q = 0.f;
    #pragma unroll
    for (int ch = 0; ch < 8; ++ch) { s += bn1s[tid*8 + ch]; q += bn1q[tid*8 + ch]; }
    const float cnt = (float)(B_*H_);
    float mu = s / cnt, var = q / cnt - mu*mu;
    float al = g1[tid] * rsqrtf(var + EPS_);
    al1[tid] = al; bt1[tid] = be1[tid] - mu*al;
  }
  __syncthreads();
  float a0 = 0.f, a1 = 0.f, a2 = 0.f;
  const float* yb = y + (size_t)b*(T_*H_);
  for (int i = tid; i < T_*H_; i += 256) {
    int t = i >> 9;
    float yn = yb[i]*al1[t] + bt1[t];
    a0 = fmaf(yn, Wl[i],            a0);
    a1 = fmaf(yn, Wl[T_*H_ + i],    a1);
    a2 = fmaf(yn, Wl[2*T_*H_ + i],  a2);
  }
  __shared__ float red[256];
  red[tid] = a0; __syncthreads();
  for (int o = 128; o; o >>= 1) { if (tid < o) red[tid] += red[tid+o]; __syncthreads(); }
  if (!tid) out[b*3 + 0] = red[0] + bl[0];
  __syncthreads();
  red[tid] = a1; __syncthreads();
  for (int o = 128; o; o >>= 1) { if (tid < o) red[tid] += red[tid+o]; __syncthreads(); }
  if (!tid) out[b*3 + 1] = red[0] + bl[1];
  __syncthreads();
  red[tid] = a2; __syncthreads();
  for (int o = 128; o; o >>= 1) { if (tid < o) red[tid] += red[tid+o]; __syncthreads(); }
  if (!tid) out[b*3 + 2] = red[0] + bl[2];
}

extern "C" void kernel_launch(void* const* d_in, const int* in_sizes, int n_in,
                              void* d_out, int out_size, void* d_ws, size_t ws_size,
                              hipStream_t stream)
{
  (void)in_sizes; (void)n_in; (void)out_size;
  const float* x   = (const float*)d_in[0];
  const int* esrc  = (const int*)d_in[1];
  const int* edst  = (const int*)d_in[2];
  const float* ew  = (const float*)d_in[3];
  const float* Wc  = (const float*)d_in[4];
  const float* bc  = (const float*)d_in[5];
  const float* bng = (const float*)d_in[6];
  const float* bnb = (const float*)d_in[7];
  const float* Wih = (const float*)d_in[8];
  const float* Whh = (const float*)d_in[9];
  const float* bih = (const float*)d_in[10];
  const float* bhh = (const float*)d_in[11];
  const float* g1  = (const float*)d_in[12];
  const float* be1 = (const float*)d_in[13];
  const float* Wl  = (const float*)d_in[14];
  const float* bl  = (const float*)d_in[15];
  float* out = (float*)d_out;

  char* ws = (char*)d_ws;
  size_t off = 0;
  auto alloc = [&](size_t bytes) {
    void* p = ws + off;
    off += (bytes + 255) & ~(size_t)255;
    return p;
  };
  float* cheb = (float*)alloc(sizeof(float)*(size_t)T_*B_*NF_);
  float* bps  = (float*)alloc(sizeof(float)*T_*F_*B_);
  float* bpq  = (float*)alloc(sizeof(float)*T_*F_*B_);
  float* alpha= (float*)alloc(sizeof(float)*T_*F_);
  float* bet  = (float*)alloc(sizeof(float)*T_*F_);
  __hip_bfloat16* seqb = (__hip_bfloat16*)alloc(sizeof(__hip_bfloat16)*(size_t)T_*B_*SEQP);
  __hip_bfloat16* Wcat = (__hip_bfloat16*)alloc(sizeof(__hip_bfloat16)*(size_t)G4*KPAD);
  float* biasr = (float*)alloc(sizeof(float)*G4);
  __hip_bfloat16* h0 = (__hip_bfloat16*)alloc(sizeof(__hip_bfloat16)*B_*H_);
  __hip_bfloat16* h1 = (__hip_bfloat16*)alloc(sizeof(__hip_bfloat16)*B_*H_);
  float* cbuf = (float*)alloc(sizeof(float)*B_*H_);
  float* y    = (float*)alloc(sizeof(float)*(size_t)B_*T_*H_);
  float* bn1s = (float*)alloc(sizeof(float)*T_*8);
  float* bn1q = (float*)alloc(sizeof(float)*T_*8);
  if (ws_size < off) return;   // ~103 MB total — within the proven round-1 footprint

  hipMemsetAsync(h0,   0, sizeof(__hip_bfloat16)*B_*H_, stream);
  hipMemsetAsync(cbuf, 0, sizeof(float)*B_*H_, stream);

  k_cheb<<<dim3(B_, T_/TC), 512, 0, stream>>>(x, esrc, edst, ew, Wc, bc, cheb, bps, bpq);
  k_bnfin<<<T_*F_, 64, 0, stream>>>(bps, bpq, bng, bnb, alpha, bet);
  k_seq<<<(T_*B_*SEQP)/256, 256, 0, stream>>>(cheb, alpha, bet, seqb);
  k_prep<<<G4, 256, 0, stream>>>(Wih, Whh, bih, bhh, Wcat, biasr);

  const __hip_bfloat16* hin = h0;
  __hip_bfloat16* hout = h1;
  for (int t = 0; t < T_; ++t) {
    k_step<<<dim3(G4/32, B_/32), 256, 0, stream>>>(
        seqb + (size_t)t*B_*SEQP, hin, Wcat, biasr, cbuf, y, hout, t);
    __hip_bfloat16* nxt = (hout == h1) ? h0 : h1;
    hin = hout;
    hout = nxt;
  }

  k_bn1part<<<dim3(T_, 8), 256, 0, stream>>>(y, bn1s, bn1q);
  k_head<<<B_, 256, 0, stream>>>(y, bn1s, bn1q, g1, be1, Wl, bl, out);
}